// Round 1
// baseline (92569.934 us; speedup 1.0000x reference)
//
#include <hip/hip_runtime.h>
#include <hip/hip_cooperative_groups.h>

namespace cg = cooperative_groups;

#define TSTEPS 1024
#define BB 128
#define HH 512
#define NCH 80
#define NATT 10
#define NG 20
#define UU 64
#define NMIX 121
#define MIXIN 592
#define LOG2PI 1.8378770664093453f

// ws float-offsets
#define OFF_WT     (2*HH*BB)                 // wT[80][128]
#define OFF_KK     (OFF_WT + NCH*BB)         // kk[128][10]
#define OFF_YH     (OFF_KK + BB*NATT)        // yh[128][121]
#define OFF_WMIXT  (OFF_YH + BB*NMIX)        // WmixT[592][121]
#define OFF_WATTT  (OFF_WMIXT + MIXIN*NMIX)  // WattT[512][32]
#define OFF_RED    (OFF_WATTT + HH*32)       // red[256]

__device__ __forceinline__ float sigmoidf(float x) { return 1.f / (1.f + expf(-x)); }

__global__ __launch_bounds__(256)
void hw_kernel(const float* __restrict__ seq_pt, const float* __restrict__ seq_mask,
               const float* __restrict__ tgt, const int* __restrict__ cidx,
               const float* __restrict__ c_mask,
               const float* __restrict__ W_ih, const float* __restrict__ b_ih,
               const float* __restrict__ W_hh, const float* __restrict__ b_hh,
               const float* __restrict__ W_att, const float* __restrict__ b_att,
               const float* __restrict__ W_mix, const float* __restrict__ b_mix,
               float* __restrict__ out, float* __restrict__ ws)
{
    const int g = blockIdx.x;
    const int tid = threadIdx.x;
    const int jblk = g >> 2;        // 0..63
    const int bblk = g & 3;         // 0..3
    const int jj = tid >> 5;        // 0..7
    const int bb = tid & 31;        // 0..31
    const int b = bblk * 32 + bb;   // batch for phase A
    const int j = jblk * 8 + jj;    // hidden unit for phase A

    __shared__ float4 s_whh[8][512];   // [jj][d] -> weights (i,f,g,o)   64KB
    __shared__ float4 s_wih[8][84];    // [jj][dd] -> (i,f,g,o)          10.75KB
    __shared__ float  s_bias[8][4];
    __shared__ float  s_m0[128];
    __shared__ float  s_m1[128];
    __shared__ float  s_m2[4];
    __shared__ int    s_ci[UU];

    // ---- load persistent LDS weights (per-WG slice) ----
    for (int idx = tid; idx < 8 * 512; idx += 256) {
        int lj = idx >> 9, d = idx & 511;
        int jg = jblk * 8 + lj;
        s_whh[lj][d] = make_float4(
            W_hh[(0 * HH + jg) * HH + d], W_hh[(1 * HH + jg) * HH + d],
            W_hh[(2 * HH + jg) * HH + d], W_hh[(3 * HH + jg) * HH + d]);
    }
    for (int idx = tid; idx < 8 * 84; idx += 256) {
        int lj = idx / 84, dd = idx % 84;
        int jg = jblk * 8 + lj;
        if (dd < 83)
            s_wih[lj][dd] = make_float4(
                W_ih[(0 * HH + jg) * 83 + dd], W_ih[(1 * HH + jg) * 83 + dd],
                W_ih[(2 * HH + jg) * 83 + dd], W_ih[(3 * HH + jg) * 83 + dd]);
        else
            s_wih[lj][dd] = make_float4(0.f, 0.f, 0.f, 0.f);
    }
    if (tid < 32) {
        int lj = tid >> 2, gg = tid & 3;
        int jg = jblk * 8 + lj;
        s_bias[lj][gg] = b_ih[gg * HH + jg] + b_hh[gg * HH + jg];
    }

    float* WmixT = ws + OFF_WMIXT;
    float* WattT = ws + OFF_WATTT;
    // ---- transpose big output weights into ws (WGs 128..255) ----
    if (g >= 128) {
        int base = (g - 128) * 256 + tid;
        for (int i = base; i < MIXIN * NMIX; i += 128 * 256) {
            int d = i / NMIX, m = i % NMIX;
            WmixT[i] = W_mix[m * MIXIN + d];
        }
        for (int i = base; i < HH * 30; i += 128 * 256) {
            int d = i / 30, m = i % 30;
            WattT[d * 32 + m] = W_att[m * HH + d];
        }
    }
    __syncthreads();

    float* hbuf0 = ws;
    float* hbuf1 = ws + HH * BB;
    float* wT = ws + OFF_WT;    // [c][b]
    float* kk = ws + OFF_KK;    // [b][10]
    float* yh = ws + OFF_YH;    // [b][121]
    float* red = ws + OFF_RED;

    float cell = 0.f;
    float nll_acc = 0.f, mask_acc = 0.f;

    cg::grid_group grid = cg::this_grid();

    for (int t = 0; t <= TSTEPS; ++t) {
        // ======== finalize NLL for step t-1 (WG g<128 owns batch g) ========
        if (t > 0 && g < BB) {
            const int fb = g;
            const int tp = t - 1;
            if (tid < 21) {
                if (tid < NG) {
                    int m = tid;
                    float ypi  = yh[fb * NMIX + m]        + b_mix[m];
                    float ymu1 = yh[fb * NMIX + 20 + m]   + b_mix[20 + m];
                    float ymu2 = yh[fb * NMIX + 40 + m]   + b_mix[40 + m];
                    float yls1 = yh[fb * NMIX + 60 + m]   + b_mix[60 + m];
                    float yls2 = yh[fb * NMIX + 80 + m]   + b_mix[80 + m];
                    float yrho = yh[fb * NMIX + 100 + m]  + b_mix[100 + m];
                    for (int c = 0; c < NCH; ++c) {
                        float wv = wT[c * BB + fb];
                        const float* wr = &WmixT[(HH + c) * NMIX];
                        ypi  = fmaf(wv, wr[m], ypi);
                        ymu1 = fmaf(wv, wr[20 + m], ymu1);
                        ymu2 = fmaf(wv, wr[40 + m], ymu2);
                        yls1 = fmaf(wv, wr[60 + m], yls1);
                        yls2 = fmaf(wv, wr[80 + m], yls2);
                        yrho = fmaf(wv, wr[100 + m], yrho);
                    }
                    const float* tg = tgt + ((size_t)tp * BB + fb) * 3;
                    float x1 = tg[0], x2 = tg[1];
                    float rho = tanhf(yrho);
                    float d1 = (x1 - ymu1) * expf(-yls1);
                    float d2 = (x2 - ymu2) * expf(-yls2);
                    float omr2 = 1.f - rho * rho;
                    float Z = d1 * d1 + d2 * d2 - 2.f * rho * d1 * d2;
                    float log_n = -Z / (2.f * omr2) - LOG2PI - yls1 - yls2 - 0.5f * logf(omr2);
                    s_m0[m] = ypi;
                    s_m1[m] = ypi + log_n;
                } else {  // tid == 20 : pen bernoulli
                    float yp = yh[fb * NMIX + 120] + b_mix[120];
                    for (int c = 0; c < NCH; ++c)
                        yp = fmaf(wT[c * BB + fb], WmixT[(HH + c) * NMIX + 120], yp);
                    const float* tg = tgt + ((size_t)tp * BB + fb) * 3;
                    float pen = tg[2];
                    float e = log1pf(expf(-fabsf(yp)));
                    float ls_p = fminf(yp, 0.f) - e;
                    float ls_n = fminf(-yp, 0.f) - e;
                    s_m2[0] = -(pen * ls_p + (1.f - pen) * ls_n);
                }
            }
            __syncthreads();
            if (tid == 0) {
                float mx1 = -1e30f, mx2 = -1e30f;
                for (int m = 0; m < NG; ++m) {
                    mx1 = fmaxf(mx1, s_m0[m]);
                    mx2 = fmaxf(mx2, s_m1[m]);
                }
                float se1 = 0.f, se2 = 0.f;
                for (int m = 0; m < NG; ++m) {
                    se1 += expf(s_m0[m] - mx1);
                    se2 += expf(s_m1[m] - mx2);
                }
                float lse_pi = mx1 + logf(se1);
                float lse_pn = mx2 + logf(se2);
                float nll = (lse_pi - lse_pn) + s_m2[0];
                float mk = seq_mask[tp * BB + fb];
                nll_acc += mk * nll;
                mask_acc += mk;
            }
        }

        if (t == TSTEPS) break;

        float* hcur = (t & 1) ? hbuf1 : hbuf0;
        const float* hprev = (t & 1) ? hbuf0 : hbuf1;

        // ======== phase A: gates + LSTM (all threads; 1 thread = (b,j)) ========
        {
            float a0 = s_bias[jj][0], a1 = s_bias[jj][1], a2 = s_bias[jj][2], a3 = s_bias[jj][3];
            const float* ip = seq_pt + ((size_t)t * BB + b) * 3;
            float x0 = ip[0], x1v = ip[1], x2v = ip[2];
            {
                float4 w0 = s_wih[jj][0], w1 = s_wih[jj][1], w2 = s_wih[jj][2];
                a0 += x0 * w0.x + x1v * w1.x + x2v * w2.x;
                a1 += x0 * w0.y + x1v * w1.y + x2v * w2.y;
                a2 += x0 * w0.z + x1v * w1.z + x2v * w2.z;
                a3 += x0 * w0.w + x1v * w1.w + x2v * w2.w;
            }
            if (t > 0) {
                #pragma unroll 4
                for (int c = 0; c < NCH; ++c) {
                    float wv = wT[c * BB + b];
                    float4 wwv = s_wih[jj][3 + c];
                    a0 = fmaf(wv, wwv.x, a0);
                    a1 = fmaf(wv, wwv.y, a1);
                    a2 = fmaf(wv, wwv.z, a2);
                    a3 = fmaf(wv, wwv.w, a3);
                }
                const float4* hp4 = (const float4*)hprev;
                #pragma unroll 4
                for (int d4 = 0; d4 < HH / 4; ++d4) {
                    float4 hv = hp4[d4 * BB + b];
                    float4 w0 = s_whh[jj][d4 * 4 + 0];
                    a0 = fmaf(hv.x, w0.x, a0); a1 = fmaf(hv.x, w0.y, a1);
                    a2 = fmaf(hv.x, w0.z, a2); a3 = fmaf(hv.x, w0.w, a3);
                    float4 w1 = s_whh[jj][d4 * 4 + 1];
                    a0 = fmaf(hv.y, w1.x, a0); a1 = fmaf(hv.y, w1.y, a1);
                    a2 = fmaf(hv.y, w1.z, a2); a3 = fmaf(hv.y, w1.w, a3);
                    float4 w2 = s_whh[jj][d4 * 4 + 2];
                    a0 = fmaf(hv.z, w2.x, a0); a1 = fmaf(hv.z, w2.y, a1);
                    a2 = fmaf(hv.z, w2.z, a2); a3 = fmaf(hv.z, w2.w, a3);
                    float4 w3 = s_whh[jj][d4 * 4 + 3];
                    a0 = fmaf(hv.w, w3.x, a0); a1 = fmaf(hv.w, w3.y, a1);
                    a2 = fmaf(hv.w, w3.z, a2); a3 = fmaf(hv.w, w3.w, a3);
                }
            }
            float ig = sigmoidf(a0);
            float fg = sigmoidf(a1);
            float gg = tanhf(a2);
            float og = sigmoidf(a3);
            cell = fg * cell + ig * gg;
            float hval = og * tanhf(cell);
            hcur[(j >> 2) * (BB * 4) + b * 4 + (j & 3)] = hval;
        }

        grid.sync();   // h_t visible everywhere

        // ======== phase B ========
        if (g < BB) {
            // attention for batch pb
            const int pb = g;
            const float4* hc4 = (const float4*)hcur;
            int m = tid & 31, half = tid >> 5;
            if (tid < 64 && m < 30) {
                float acc = 0.f;
                for (int d4 = half * 64; d4 < half * 64 + 64; ++d4) {
                    float4 hv = hc4[d4 * BB + pb];
                    int d = d4 * 4;
                    acc = fmaf(hv.x, WattT[(d + 0) * 32 + m], acc);
                    acc = fmaf(hv.y, WattT[(d + 1) * 32 + m], acc);
                    acc = fmaf(hv.z, WattT[(d + 2) * 32 + m], acc);
                    acc = fmaf(hv.w, WattT[(d + 3) * 32 + m], acc);
                }
                if (half == 0) s_m0[m] = acc; else s_m1[m] = acc;
            }
            __syncthreads();
            if (tid < 30) s_m0[tid] = s_m0[tid] + s_m1[tid] + b_att[tid];
            __syncthreads();
            float mk = seq_mask[t * BB + pb];
            if (tid < NATT) {
                float ah = s_m0[tid], bh = s_m0[10 + tid], kh = s_m0[20 + tid];
                float kprev = (t > 0) ? kk[pb * NATT + tid] : 0.f;
                float kn = kprev + expf(kh);
                s_m1[tid] = expf(ah);
                s_m1[16 + tid] = expf(bh);
                s_m1[32 + tid] = kn;
                kk[pb * NATT + tid] = mk * kn + (1.f - mk) * kprev;
            }
            __syncthreads();
            if (tid < UU) {
                float uu = (float)tid;
                float phi = 0.f;
                #pragma unroll
                for (int a = 0; a < NATT; ++a) {
                    float diff = s_m1[32 + a] - uu;
                    phi = fmaf(s_m1[a], expf(-s_m1[16 + a] * diff * diff), phi);
                }
                phi *= c_mask[tid * BB + pb];
                s_m0[64 + tid] = phi;
                s_ci[tid] = cidx[tid * BB + pb];
            }
            __syncthreads();
            if (tid < NCH) {
                float wn = 0.f;
                for (int u = 0; u < UU; ++u)
                    wn += (s_ci[u] == tid) ? s_m0[64 + u] : 0.f;
                float wold = (t > 0) ? wT[tid * BB + pb] : 0.f;
                wT[tid * BB + pb] = mk * wn + (1.f - mk) * wold;
            }
        } else {
            // mixture-projection h-part for batch pb
            const int pb = g - 128;
            const float4* hc4 = (const float4*)hcur;
            int m = tid & 127, half = tid >> 7;
            if (m < NMIX) {
                float acc = 0.f;
                for (int d4 = half * 64; d4 < half * 64 + 64; ++d4) {
                    float4 hv = hc4[d4 * BB + pb];
                    int d = d4 * 4;
                    acc = fmaf(hv.x, WmixT[(d + 0) * NMIX + m], acc);
                    acc = fmaf(hv.y, WmixT[(d + 1) * NMIX + m], acc);
                    acc = fmaf(hv.z, WmixT[(d + 2) * NMIX + m], acc);
                    acc = fmaf(hv.w, WmixT[(d + 3) * NMIX + m], acc);
                }
                if (half == 0) s_m0[m] = acc; else s_m1[m] = acc;
            }
            __syncthreads();
            if (tid < NMIX) yh[pb * NMIX + tid] = s_m0[tid] + s_m1[tid];
        }

        grid.sync();   // w_t, y_h visible everywhere
    }

    // ======== final reduction ========
    if (g < BB && tid == 0) {
        red[g] = nll_acc;
        red[BB + g] = mask_acc;
    }
    grid.sync();
    if (g == 0 && tid == 0) {
        float sn = 0.f, sm = 0.f;
        for (int i = 0; i < BB; ++i) { sn += red[i]; sm += red[BB + i]; }
        out[0] = sn / sm;
    }
}

extern "C" void kernel_launch(void* const* d_in, const int* in_sizes, int n_in,
                              void* d_out, int out_size, void* d_ws, size_t ws_size,
                              hipStream_t stream) {
    const float* seq_pt   = (const float*)d_in[0];
    const float* seq_mask = (const float*)d_in[1];
    const float* tgt      = (const float*)d_in[2];
    const int*   cidx     = (const int*)d_in[3];
    const float* c_mask   = (const float*)d_in[4];
    const float* W_ih     = (const float*)d_in[5];
    const float* b_ih     = (const float*)d_in[6];
    const float* W_hh     = (const float*)d_in[7];
    const float* b_hh     = (const float*)d_in[8];
    const float* W_att    = (const float*)d_in[9];
    const float* b_att    = (const float*)d_in[10];
    const float* W_mix    = (const float*)d_in[11];
    const float* b_mix    = (const float*)d_in[12];
    float* out = (float*)d_out;
    float* ws  = (float*)d_ws;

    void* args[] = {&seq_pt, &seq_mask, &tgt, &cidx, &c_mask,
                    &W_ih, &b_ih, &W_hh, &b_hh, &W_att, &b_att,
                    &W_mix, &b_mix, &out, &ws};
    hipLaunchCooperativeKernel((void*)hw_kernel, dim3(256), dim3(256), args, 0, stream);
}

// Round 3
// 28297.717 us; speedup vs baseline: 3.2713x; 3.2713x over previous
//
#include <hip/hip_runtime.h>

#define TSTEPS 1024
#define BB 128
#define HH 512
#define NCH 80
#define NATT 10
#define NG 20
#define UU 64
#define NMIX 121
#define LOG2PI 1.8378770664093453f

// ws float offsets
#define OFF_HA0 0
#define OFF_HA1 65536
#define OFF_HB  131072
#define OFF_WT  196608
#define OFF_YH  206848
#define OFF_RED 222336
#define OFF_SYNC 222720
#define SYNC_WORDS 4128   // 256 slots * 16 words + release word (+pad)

__device__ __forceinline__ float ld_scf(const float* p) {
    return __hip_atomic_load((float*)p, __ATOMIC_RELAXED, __HIP_MEMORY_SCOPE_AGENT);
}
__device__ __forceinline__ void st_scf(float* p, float v) {
    __hip_atomic_store(p, v, __ATOMIC_RELAXED, __HIP_MEMORY_SCOPE_AGENT);
}
__device__ __forceinline__ float2 ld_sc2(const float* p) {
    unsigned long long v = __hip_atomic_load((unsigned long long*)p, __ATOMIC_RELAXED, __HIP_MEMORY_SCOPE_AGENT);
    float2 f; __builtin_memcpy(&f, &v, 8); return f;
}
__device__ __forceinline__ unsigned ld_u(const unsigned* p) {
    return __hip_atomic_load((unsigned*)p, __ATOMIC_RELAXED, __HIP_MEMORY_SCOPE_AGENT);
}
__device__ __forceinline__ void st_u(unsigned* p, unsigned v) {
    __hip_atomic_store(p, v, __ATOMIC_RELAXED, __HIP_MEMORY_SCOPE_AGENT);
}

__global__ void init_sync_kernel(float* ws) {
    unsigned* s = (unsigned*)(ws + OFF_SYNC);
    for (int i = threadIdx.x; i < SYNC_WORDS; i += blockDim.x)
        st_u(s + i, 0u);
}

// zero-contention barrier: per-WG arrival slot (64B apart), WG0's 256 threads
// poll the 256 slots in parallel, then WG0 publishes the epoch.
__device__ __forceinline__ void gbar(unsigned* sl, int g, int tid, unsigned bar) {
    asm volatile("s_waitcnt vmcnt(0)" ::: "memory");  // all sc1 data stores globally visible
    __syncthreads();
    if (tid == 0) st_u(sl + g * 16, bar);
    if (g == 0) {
        while (ld_u(sl + tid * 16) < bar) __builtin_amdgcn_s_sleep(2);
        __syncthreads();
        if (tid == 0) st_u(sl + 256 * 16, bar);
    } else {
        if (tid == 0) {
            while (ld_u(sl + 256 * 16) < bar) __builtin_amdgcn_s_sleep(2);
        }
        __syncthreads();
    }
}

__global__ __launch_bounds__(256)
void hw_kernel(const float* __restrict__ seq_pt, const float* __restrict__ seq_mask,
               const float* __restrict__ tgt, const int* __restrict__ cidx,
               const float* __restrict__ c_mask,
               const float* __restrict__ W_ih, const float* __restrict__ b_ih,
               const float* __restrict__ W_hh, const float* __restrict__ b_hh,
               const float* __restrict__ W_att, const float* __restrict__ b_att,
               const float* __restrict__ W_mix, const float* __restrict__ b_mix,
               float* __restrict__ out, float* __restrict__ ws)
{
    const int g = blockIdx.x;
    const int tid = threadIdx.x;
    const int jblk = g >> 2;        // 0..63  (8 hidden units each)
    const int bblk = g & 3;         // 0..3   (32 batches each)
    // phase-A FMA role
    const int jj  = tid & 7;        // j within block
    const int bg3 = (tid >> 3) & 7; // batch-quad within the 32
    const int ks  = tid >> 6;       // d-split (wave index)

    // LDS ~112 KB total
    __shared__ float4 s_wW[8][601];               // 76928 B: [j][0..511]=W_hh d, [512..591]=W_ih w, [592..594]=W_ih x, [595]=bias
    __shared__ __align__(16) float s_chm[8192];   // 32768 B: two 16KB chunk buffers / red / phase-B h
    __shared__ float s_pA[256], s_pB[96];
    __shared__ float s_wold[NCH], s_kk[16];
    __shared__ float s_phi[64];
    __shared__ int   s_ci[64];
    __shared__ float s_nA[20], s_nB[20], s_pen[1];

    // ---- persistent LDS weights (once; plain cached loads of read-only inputs) ----
    for (int lin = tid; lin < 8 * 596; lin += 256) {
        int lj = lin / 596, idx = lin % 596;
        int jg = jblk * 8 + lj;
        float4 v;
        if (idx < 512) {
            v = make_float4(W_hh[(0 * HH + jg) * HH + idx], W_hh[(1 * HH + jg) * HH + idx],
                            W_hh[(2 * HH + jg) * HH + idx], W_hh[(3 * HH + jg) * HH + idx]);
        } else if (idx < 592) {
            int dd = 3 + (idx - 512);
            v = make_float4(W_ih[(0 * HH + jg) * 83 + dd], W_ih[(1 * HH + jg) * 83 + dd],
                            W_ih[(2 * HH + jg) * 83 + dd], W_ih[(3 * HH + jg) * 83 + dd]);
        } else if (idx < 595) {
            int dd = idx - 592;
            v = make_float4(W_ih[(0 * HH + jg) * 83 + dd], W_ih[(1 * HH + jg) * 83 + dd],
                            W_ih[(2 * HH + jg) * 83 + dd], W_ih[(3 * HH + jg) * 83 + dd]);
        } else {
            v = make_float4(b_ih[0 * HH + jg] + b_hh[0 * HH + jg], b_ih[1 * HH + jg] + b_hh[1 * HH + jg],
                            b_ih[2 * HH + jg] + b_hh[2 * HH + jg], b_ih[3 * HH + jg] + b_hh[3 * HH + jg]);
        }
        s_wW[lj][idx] = v;
    }
    if (tid < 16) s_kk[tid] = 0.f;
    __syncthreads();

    unsigned* syncp = (unsigned*)(ws + OFF_SYNC);
    float* hB  = ws + OFF_HB;   // [b][d]  (for phase B)
    float* wT  = ws + OFF_WT;   // [c][b]
    float* yh  = ws + OFF_YH;   // [b][121]
    float* red = ws + OFF_RED;

    float cell = 0.f, nll_acc = 0.f, mask_acc = 0.f;
    unsigned bar = 0;

    for (int t = 0; t <= TSTEPS; ++t) {
        // ======== NLL for step t-1 (WG g<128 owns batch g; w(t-1) in s_wold) ========
        if (t > 0 && g < BB) {
            const int fb = g, tp = t - 1;
            if (tid < 21) {
                if (tid < NG) {
                    int m = tid;
                    float y0 = ld_scf(&yh[fb * NMIX + m])       + b_mix[m];
                    float y1 = ld_scf(&yh[fb * NMIX + 20 + m])  + b_mix[20 + m];
                    float y2 = ld_scf(&yh[fb * NMIX + 40 + m])  + b_mix[40 + m];
                    float y3 = ld_scf(&yh[fb * NMIX + 60 + m])  + b_mix[60 + m];
                    float y4 = ld_scf(&yh[fb * NMIX + 80 + m])  + b_mix[80 + m];
                    float y5 = ld_scf(&yh[fb * NMIX + 100 + m]) + b_mix[100 + m];
                    const float* r0 = W_mix + (size_t)(m)       * 592 + 512;
                    const float* r1 = W_mix + (size_t)(20 + m)  * 592 + 512;
                    const float* r2 = W_mix + (size_t)(40 + m)  * 592 + 512;
                    const float* r3 = W_mix + (size_t)(60 + m)  * 592 + 512;
                    const float* r4 = W_mix + (size_t)(80 + m)  * 592 + 512;
                    const float* r5 = W_mix + (size_t)(100 + m) * 592 + 512;
                    for (int c = 0; c < NCH; ++c) {
                        float wv = s_wold[c];
                        y0 = fmaf(wv, r0[c], y0); y1 = fmaf(wv, r1[c], y1);
                        y2 = fmaf(wv, r2[c], y2); y3 = fmaf(wv, r3[c], y3);
                        y4 = fmaf(wv, r4[c], y4); y5 = fmaf(wv, r5[c], y5);
                    }
                    const float* tg = tgt + ((size_t)tp * BB + fb) * 3;
                    float x1 = tg[0], x2 = tg[1];
                    float rho = tanhf(y5);
                    float d1 = (x1 - y1) * expf(-y3);
                    float d2 = (x2 - y2) * expf(-y4);
                    float omr2 = 1.f - rho * rho;
                    float Z = d1 * d1 + d2 * d2 - 2.f * rho * d1 * d2;
                    float log_n = -Z / (2.f * omr2) - LOG2PI - y3 - y4 - 0.5f * logf(omr2);
                    s_nA[m] = y0;
                    s_nB[m] = y0 + log_n;
                } else {
                    float yp = ld_scf(&yh[fb * NMIX + 120]) + b_mix[120];
                    const float* rp = W_mix + (size_t)120 * 592 + 512;
                    for (int c = 0; c < NCH; ++c) yp = fmaf(s_wold[c], rp[c], yp);
                    const float* tg = tgt + ((size_t)tp * BB + fb) * 3;
                    float pen = tg[2];
                    float e = log1pf(expf(-fabsf(yp)));
                    float ls_p = fminf(yp, 0.f) - e;
                    float ls_n = fminf(-yp, 0.f) - e;
                    s_pen[0] = -(pen * ls_p + (1.f - pen) * ls_n);
                }
            }
            __syncthreads();
            if (tid == 0) {
                float mx1 = -1e30f, mx2 = -1e30f;
                for (int m = 0; m < NG; ++m) { mx1 = fmaxf(mx1, s_nA[m]); mx2 = fmaxf(mx2, s_nB[m]); }
                float se1 = 0.f, se2 = 0.f;
                for (int m = 0; m < NG; ++m) { se1 += expf(s_nA[m] - mx1); se2 += expf(s_nB[m] - mx2); }
                float nll = (mx1 + logf(se1)) - (mx2 + logf(se2)) + s_pen[0];
                float mk = seq_mask[(size_t)tp * BB + fb];
                nll_acc += mk * nll;
                mask_acc += mk;
            }
        }

        if (t == TSTEPS) break;

        float* hAcur = ws + ((t & 1) ? OFF_HA1 : OFF_HA0);
        const float* hAprv = ws + ((t & 1) ? OFF_HA0 : OFF_HA1);

        // ======== phase A: chunked staging + R=4 gate GEMM ========
        float4 a0 = make_float4(0.f, 0.f, 0.f, 0.f);
        float4 a1 = a0, a2 = a0, a3 = a0;

        if (t > 0) {
            float2 stg[8];
            auto fma_chunk = [&](int nd, int base, int w0, const float* cb) {
                #pragma unroll 4
                for (int dl = 0; dl < nd; ++dl) {
                    float4 wv = s_wW[jj][w0 + dl];
                    const float4 hv = *(const float4*)&cb[(base + dl) * 32 + bg3 * 4];
                    a0.x = fmaf(hv.x, wv.x, a0.x); a0.y = fmaf(hv.x, wv.y, a0.y);
                    a0.z = fmaf(hv.x, wv.z, a0.z); a0.w = fmaf(hv.x, wv.w, a0.w);
                    a1.x = fmaf(hv.y, wv.x, a1.x); a1.y = fmaf(hv.y, wv.y, a1.y);
                    a1.z = fmaf(hv.y, wv.z, a1.z); a1.w = fmaf(hv.y, wv.w, a1.w);
                    a2.x = fmaf(hv.z, wv.x, a2.x); a2.y = fmaf(hv.z, wv.y, a2.y);
                    a2.z = fmaf(hv.z, wv.z, a2.z); a2.w = fmaf(hv.z, wv.w, a2.w);
                    a3.x = fmaf(hv.w, wv.x, a3.x); a3.y = fmaf(hv.w, wv.y, a3.y);
                    a3.z = fmaf(hv.w, wv.z, a3.z); a3.w = fmaf(hv.w, wv.w, a3.w);
                }
            };
            // stage chunk 0 (h d 0..127)
            #pragma unroll
            for (int i = 0; i < 8; ++i) {
                int lin = i * 256 + tid, d = lin >> 4, c2 = lin & 15;
                stg[i] = ld_sc2(hAprv + (size_t)d * BB + bblk * 32 + c2 * 2);
            }
            #pragma unroll
            for (int i = 0; i < 8; ++i) {
                int lin = i * 256 + tid, d = lin >> 4, c2 = lin & 15;
                ((float2*)s_chm)[d * 16 + c2] = stg[i];
            }
            __syncthreads();
            #pragma unroll 1
            for (int r = 0; r < 5; ++r) {
                // issue next chunk's global loads (latency hides under FMA)
                if (r < 3) {
                    #pragma unroll
                    for (int i = 0; i < 8; ++i) {
                        int lin = i * 256 + tid, d = lin >> 4, c2 = lin & 15;
                        stg[i] = ld_sc2(hAprv + (size_t)((r + 1) * 128 + d) * BB + bblk * 32 + c2 * 2);
                    }
                } else if (r == 3) {
                    #pragma unroll
                    for (int i = 0; i < 5; ++i) {
                        int lin = i * 256 + tid, d = lin >> 4, c2 = lin & 15;
                        stg[i] = ld_sc2(wT + (size_t)d * BB + bblk * 32 + c2 * 2);
                    }
                }
                // FMA on current chunk
                const float* cb = s_chm + (r & 1) * 4096;
                if (r < 4) fma_chunk(32, ks * 32, r * 128 + ks * 32, cb);
                else       fma_chunk(20, ks * 20, 512 + ks * 20, cb);
                // write staged chunk to the other buffer
                if (r < 4) {
                    float* wb = s_chm + ((r + 1) & 1) * 4096;
                    int n2 = (r < 3) ? 8 : 5;
                    for (int i = 0; i < n2; ++i) {
                        int lin = i * 256 + tid, d = lin >> 4, c2 = lin & 15;
                        ((float2*)wb)[d * 16 + c2] = stg[i];
                    }
                    __syncthreads();
                }
            }
            // partials -> red (= chunk buffer 1; safe: chunk 4 FMA reads buffer 0)
            {
                float* rd = s_chm + 4096;
                int row = ((ks * 8 + jj) * 8 + bg3) * 16;
                *(float4*)&rd[row + 0]  = a0;
                *(float4*)&rd[row + 4]  = a1;
                *(float4*)&rd[row + 8]  = a2;
                *(float4*)&rd[row + 12] = a3;
            }
            __syncthreads();
        }

        // pointwise LSTM: thread = (j, b) output owner
        {
            const int jj_o = tid >> 5, bl = tid & 31;
            const int b = bblk * 32 + bl, j = jblk * 8 + jj_o;
            float4 s = s_wW[jj_o][595];  // bias
            if (t > 0) {
                const float* rd = s_chm + 4096;
                #pragma unroll
                for (int k2 = 0; k2 < 4; ++k2) {
                    int row = ((k2 * 8 + jj_o) * 8 + (bl >> 2)) * 16 + (bl & 3) * 4;
                    float4 v = *(const float4*)&rd[row];
                    s.x += v.x; s.y += v.y; s.z += v.z; s.w += v.w;
                }
            }
            const float* ip = seq_pt + ((size_t)t * BB + b) * 3;
            float x0 = ip[0], x1 = ip[1], x2 = ip[2];
            float4 wx0 = s_wW[jj_o][592], wx1 = s_wW[jj_o][593], wx2 = s_wW[jj_o][594];
            s.x += x0 * wx0.x + x1 * wx1.x + x2 * wx2.x;
            s.y += x0 * wx0.y + x1 * wx1.y + x2 * wx2.y;
            s.z += x0 * wx0.z + x1 * wx1.z + x2 * wx2.z;
            s.w += x0 * wx0.w + x1 * wx1.w + x2 * wx2.w;
            float ig = 1.f / (1.f + expf(-s.x));
            float fg = 1.f / (1.f + expf(-s.y));
            float gg = tanhf(s.z);
            float og = 1.f / (1.f + expf(-s.w));
            cell = fg * cell + ig * gg;
            float hval = og * tanhf(cell);
            st_scf(hAcur + (size_t)j * BB + b, hval);       // [d][b] for phase-A staging
            st_scf(hB + (size_t)b * HH + j, hval);          // [b][d] for phase B
        }

        ++bar; gbar(syncp, g, tid, bar);   // h_t globally visible

        // ======== phase B ========
        {
            const int pb = (g < BB) ? g : (g - BB);
            float* s_h = s_chm;
            s_h[tid]       = ld_scf(hB + (size_t)pb * HH + tid);
            s_h[256 + tid] = ld_scf(hB + (size_t)pb * HH + 256 + tid);
            __syncthreads();
            float mk = seq_mask[(size_t)t * BB + pb];
            if (g < BB) {
                // attention
                int m = tid & 31, oct = tid >> 5;
                if (m < 30) {
                    const float* wa = W_att + (size_t)m * HH + oct * 64;
                    const float* hb = s_h + oct * 64;
                    float acc = 0.f;
                    #pragma unroll 8
                    for (int d = 0; d < 64; ++d) acc = fmaf(hb[d], wa[d], acc);
                    s_pA[oct * 32 + m] = acc;
                }
                __syncthreads();
                if (tid < 30) {
                    float v = b_att[tid];
                    #pragma unroll
                    for (int o = 0; o < 8; ++o) v += s_pA[o * 32 + tid];
                    s_pB[tid] = v;
                }
                __syncthreads();
                if (tid < NATT) {
                    float ah = s_pB[tid], bh = s_pB[10 + tid], kh = s_pB[20 + tid];
                    float kprev = s_kk[tid];
                    float kn = kprev + expf(kh);
                    s_pB[32 + tid] = expf(ah);
                    s_pB[48 + tid] = expf(bh);
                    s_pB[64 + tid] = kn;
                    s_kk[tid] = mk * kn + (1.f - mk) * kprev;
                }
                __syncthreads();
                if (tid < UU) {
                    float uu = (float)tid;
                    float phi = 0.f;
                    #pragma unroll
                    for (int a = 0; a < NATT; ++a) {
                        float diff = s_pB[64 + a] - uu;
                        phi = fmaf(s_pB[32 + a], expf(-s_pB[48 + a] * diff * diff), phi);
                    }
                    s_phi[tid] = phi * c_mask[(size_t)tid * BB + pb];
                    s_ci[tid] = cidx[(size_t)tid * BB + pb];
                }
                __syncthreads();
                if (tid < NCH) {
                    float wn = 0.f;
                    for (int u = 0; u < UU; ++u)
                        wn += (s_ci[u] == tid) ? s_phi[u] : 0.f;
                    float wold = (t > 0) ? s_wold[tid] : 0.f;
                    float wnew = mk * wn + (1.f - mk) * wold;
                    s_wold[tid] = wnew;
                    st_scf(wT + (size_t)tid * BB + pb, wnew);
                }
            } else {
                // mixture h-part
                if (tid < 242) {
                    int m = tid >> 1, hf = tid & 1;
                    const float* wm = W_mix + (size_t)m * 592 + hf * 256;
                    const float* hb = s_h + hf * 256;
                    float acc = 0.f;
                    #pragma unroll 8
                    for (int d = 0; d < 256; ++d) acc = fmaf(hb[d], wm[d], acc);
                    s_pA[tid] = acc;
                }
                __syncthreads();
                if (tid < NMIX)
                    st_scf(yh + (size_t)pb * NMIX + tid, s_pA[2 * tid] + s_pA[2 * tid + 1]);
            }
        }

        ++bar; gbar(syncp, g, tid, bar);   // w_t, yh_t globally visible
    }

    // ======== final reduction ========
    if (g < BB && tid == 0) {
        st_scf(red + g, nll_acc);
        st_scf(red + BB + g, mask_acc);
    }
    ++bar; gbar(syncp, g, tid, bar);
    if (g == 0 && tid == 0) {
        float sn = 0.f, sm = 0.f;
        for (int i = 0; i < BB; ++i) { sn += ld_scf(red + i); sm += ld_scf(red + BB + i); }
        out[0] = sn / sm;
    }
}

extern "C" void kernel_launch(void* const* d_in, const int* in_sizes, int n_in,
                              void* d_out, int out_size, void* d_ws, size_t ws_size,
                              hipStream_t stream) {
    (void)in_sizes; (void)n_in; (void)out_size; (void)ws_size;
    const float* seq_pt   = (const float*)d_in[0];
    const float* seq_mask = (const float*)d_in[1];
    const float* tgt      = (const float*)d_in[2];
    const int*   cidx     = (const int*)d_in[3];
    const float* c_mask   = (const float*)d_in[4];
    const float* W_ih     = (const float*)d_in[5];
    const float* b_ih     = (const float*)d_in[6];
    const float* W_hh     = (const float*)d_in[7];
    const float* b_hh     = (const float*)d_in[8];
    const float* W_att    = (const float*)d_in[9];
    const float* b_att    = (const float*)d_in[10];
    const float* W_mix    = (const float*)d_in[11];
    const float* b_mix    = (const float*)d_in[12];
    float* out = (float*)d_out;
    float* ws  = (float*)d_ws;

    hipLaunchKernelGGL(init_sync_kernel, dim3(1), dim3(256), 0, stream, ws);

    void* args[] = {&seq_pt, &seq_mask, &tgt, &cidx, &c_mask,
                    &W_ih, &b_ih, &W_hh, &b_hh, &W_att, &b_att,
                    &W_mix, &b_mix, &out, &ws};
    hipError_t e = hipLaunchCooperativeKernel((void*)hw_kernel, dim3(256), dim3(256), args, 0, stream);
    if (e != hipSuccess) {
        (void)hipGetLastError();  // clear error state; fall back to plain launch
        hipLaunchKernelGGL(hw_kernel, dim3(256), dim3(256), 0, stream,
                           seq_pt, seq_mask, tgt, cidx, c_mask,
                           W_ih, b_ih, W_hh, b_hh, W_att, b_att,
                           W_mix, b_mix, out, ws);
    }
}

// Round 4
// 23798.643 us; speedup vs baseline: 3.8897x; 1.1890x over previous
//
#include <hip/hip_runtime.h>

#define TSTEPS 1024
#define BB 128
#define HH 512
#define NCH 80
#define NATT 10
#define NG 20
#define UU 64
#define LOG2PI 1.8378770664093453f

// ws float offsets
#define OFF_HA0 0
#define OFF_HA1 65536
#define OFF_HB  131072
#define OFF_WT  196608
#define OFF_YH  206848
#define OFF_WMW 223232
#define OFF_RED 233472
#define OFF_SYNC 233728
#define SYNC_WORDS 4240   // 256 arrival slots*16 + release + 8 replicas

__device__ __forceinline__ float ld_scf(const float* p) {
    return __hip_atomic_load((float*)p, __ATOMIC_RELAXED, __HIP_MEMORY_SCOPE_AGENT);
}
__device__ __forceinline__ void st_scf(float* p, float v) {
    __hip_atomic_store(p, v, __ATOMIC_RELAXED, __HIP_MEMORY_SCOPE_AGENT);
}
__device__ __forceinline__ float2 ld_sc2(const float* p) {
    unsigned long long v = __hip_atomic_load((unsigned long long*)p, __ATOMIC_RELAXED, __HIP_MEMORY_SCOPE_AGENT);
    float2 f; __builtin_memcpy(&f, &v, 8); return f;
}
__device__ __forceinline__ unsigned ld_u(const unsigned* p) {
    return __hip_atomic_load((unsigned*)p, __ATOMIC_RELAXED, __HIP_MEMORY_SCOPE_AGENT);
}
__device__ __forceinline__ void st_u(unsigned* p, unsigned v) {
    __hip_atomic_store(p, v, __ATOMIC_RELAXED, __HIP_MEMORY_SCOPE_AGENT);
}

__global__ void init_sync_kernel(float* ws) {
    unsigned* s = (unsigned*)(ws + OFF_SYNC);
    for (int i = threadIdx.x; i < SYNC_WORDS; i += blockDim.x) st_u(s + i, 0u);
}

// barrier: per-WG arrival slots; WG0 polls all 256 in parallel, releases via 8 replicated lines
__device__ __forceinline__ void gbar(unsigned* sl, int g, int tid, unsigned bar) {
    asm volatile("s_waitcnt vmcnt(0)" ::: "memory");
    __syncthreads();
    if (g == 0) {
        if (tid == 0) st_u(sl + 0, bar);
        while (ld_u(sl + tid * 16) < bar) __builtin_amdgcn_s_sleep(1);
        __syncthreads();
        if (tid < 8) st_u(sl + (257 + tid) * 16, bar);
    } else {
        if (tid == 0) {
            st_u(sl + g * 16, bar);
            while (ld_u(sl + (257 + (g & 7)) * 16) < bar) __builtin_amdgcn_s_sleep(1);
        }
        __syncthreads();
    }
}

__global__ __launch_bounds__(256)
void hw_kernel(const float* __restrict__ seq_pt, const float* __restrict__ seq_mask,
               const float* __restrict__ tgt, const int* __restrict__ cidx,
               const float* __restrict__ c_mask,
               const float* __restrict__ W_ih, const float* __restrict__ b_ih,
               const float* __restrict__ W_hh, const float* __restrict__ b_hh,
               const float* __restrict__ W_att, const float* __restrict__ b_att,
               const float* __restrict__ W_mix, const float* __restrict__ b_mix,
               float* __restrict__ out, float* __restrict__ ws)
{
    const int g = blockIdx.x;
    const int tid = threadIdx.x;
    const int jblk = g >> 2;        // 0..63  (8 hidden units)
    const int bblk = g & 3;         // 0..3   (32 batches)
    // phase-A FMA role
    const int jj  = tid & 7;
    const int bg3 = (tid >> 3) & 7;
    const int ks  = tid >> 6;       // wave = d-split

    __shared__ float4 s_wW[8][601];              // 76.9 KB: [j][0..511]=W_hh, [512..591]=W_ih(w), [592..594]=W_ih(x), [595]=bias
    __shared__ __align__(16) float s_chm[9216];  // 36.9 KB: 3 x 3072-float chunk buffers (partials overlay)
    __shared__ float s_y[124];
    __shared__ float s_pA[256], s_pB[96];
    __shared__ float s_wold[NCH], s_kk[16];
    __shared__ float s_phi[64];
    __shared__ int   s_ci[64];
    __shared__ float s_nA[20], s_nB[20], s_pen[1];

    // ---- persistent LDS weights ----
    for (int lin = tid; lin < 8 * 596; lin += 256) {
        int lj = lin / 596, idx = lin % 596;
        int jg = jblk * 8 + lj;
        float4 v;
        if (idx < 512) {
            v = make_float4(W_hh[(0 * HH + jg) * HH + idx], W_hh[(1 * HH + jg) * HH + idx],
                            W_hh[(2 * HH + jg) * HH + idx], W_hh[(3 * HH + jg) * HH + idx]);
        } else if (idx < 592) {
            int dd = 3 + (idx - 512);
            v = make_float4(W_ih[(0 * HH + jg) * 83 + dd], W_ih[(1 * HH + jg) * 83 + dd],
                            W_ih[(2 * HH + jg) * 83 + dd], W_ih[(3 * HH + jg) * 83 + dd]);
        } else if (idx < 595) {
            int dd = idx - 592;
            v = make_float4(W_ih[(0 * HH + jg) * 83 + dd], W_ih[(1 * HH + jg) * 83 + dd],
                            W_ih[(2 * HH + jg) * 83 + dd], W_ih[(3 * HH + jg) * 83 + dd]);
        } else {
            v = make_float4(b_ih[0 * HH + jg] + b_hh[0 * HH + jg], b_ih[1 * HH + jg] + b_hh[1 * HH + jg],
                            b_ih[2 * HH + jg] + b_hh[2 * HH + jg], b_ih[3 * HH + jg] + b_hh[3 * HH + jg]);
        }
        s_wW[lj][idx] = v;
    }
    if (tid < 16) s_kk[tid] = 0.f;

    float* WMW = ws + OFF_WMW;   // [c][128] transposed W_mix w-part+pen
    {   // write once (all WGs, strided); visible after first barrier
        int i = g * 256 + tid;
        if (i < NCH * 121) {
            int c = i / 121, m = i % 121;
            st_scf(&WMW[c * 128 + m], W_mix[(size_t)m * 592 + 512 + c]);
        }
    }
    __syncthreads();

    unsigned* syncp = (unsigned*)(ws + OFF_SYNC);
    float* hB  = ws + OFF_HB;    // [b][d]
    float* wT  = ws + OFF_WT;    // [c][b]
    float* yh  = ws + OFF_YH;    // [b][128]
    float* red = ws + OFF_RED;

    float cell = 0.f, nll_acc = 0.f, mask_acc = 0.f;
    unsigned bar = 0;

    for (int t = 0; t <= TSTEPS; ++t) {
        // ======== NLL for step t-1 (WG g<128 owns batch g; w(t-1) in s_wold) ========
        if (t > 0 && g < BB) {
            const int fb = g, tp = t - 1;
            if (tid < 121) {
                float acc = ld_scf(&yh[fb * 128 + tid]) + b_mix[tid];
                #pragma unroll 8
                for (int c = 0; c < NCH; ++c)
                    acc = fmaf(s_wold[c], ld_scf(&WMW[c * 128 + tid]), acc);
                s_y[tid] = acc;
            }
            __syncthreads();
            if (tid < 21) {
                const float* tg = tgt + ((size_t)tp * BB + fb) * 3;
                if (tid < NG) {
                    int m = tid;
                    float y0 = s_y[m], y1 = s_y[20 + m], y2 = s_y[40 + m];
                    float y3 = s_y[60 + m], y4 = s_y[80 + m], y5 = s_y[100 + m];
                    float x1 = tg[0], x2 = tg[1];
                    float rho = tanhf(y5);
                    float d1 = (x1 - y1) * expf(-y3);
                    float d2 = (x2 - y2) * expf(-y4);
                    float omr2 = 1.f - rho * rho;
                    float Z = d1 * d1 + d2 * d2 - 2.f * rho * d1 * d2;
                    float log_n = -Z / (2.f * omr2) - LOG2PI - y3 - y4 - 0.5f * logf(omr2);
                    s_nA[m] = y0;
                    s_nB[m] = y0 + log_n;
                } else {
                    float yp = s_y[120];
                    float pen = tg[2];
                    float e = log1pf(expf(-fabsf(yp)));
                    float ls_p = fminf(yp, 0.f) - e;
                    float ls_n = fminf(-yp, 0.f) - e;
                    s_pen[0] = -(pen * ls_p + (1.f - pen) * ls_n);
                }
            }
            __syncthreads();
            if (tid == 0) {
                float mx1 = -1e30f, mx2 = -1e30f;
                for (int m = 0; m < NG; ++m) { mx1 = fmaxf(mx1, s_nA[m]); mx2 = fmaxf(mx2, s_nB[m]); }
                float se1 = 0.f, se2 = 0.f;
                for (int m = 0; m < NG; ++m) { se1 += expf(s_nA[m] - mx1); se2 += expf(s_nB[m] - mx2); }
                float nll = (mx1 + logf(se1)) - (mx2 + logf(se2)) + s_pen[0];
                float mk = seq_mask[(size_t)tp * BB + fb];
                nll_acc += mk * nll;
                mask_acc += mk;
            }
        }

        if (t == TSTEPS) break;

        float* hAcur = ws + ((t & 1) ? OFF_HA1 : OFF_HA0);
        const float* hAprv = ws + ((t & 1) ? OFF_HA0 : OFF_HA1);

        // ======== phase A: 7x96-row chunks, 3 LDS buffers, 2-deep prefetch ========
        float4 a0 = make_float4(0.f, 0.f, 0.f, 0.f);
        float4 a1 = a0, a2 = a0, a3 = a0;

        if (t > 0) {
            float2 rgA[6], rgB[6];
            auto stage_issue = [&](int r, float2* rg) {
                #pragma unroll
                for (int i = 0; i < 6; ++i) {
                    if (i == 0 || r < 6) {
                        int lin = i * 256 + tid;
                        int dR = lin >> 4, c2 = lin & 15;
                        int R = r * 96 + dR;
                        const float* src = (R < 512) ? (hAprv + (size_t)R * BB)
                                                     : (wT + (size_t)(R - 512) * BB);
                        rg[i] = ld_sc2(src + bblk * 32 + c2 * 2);
                    }
                }
            };
            auto stage_write = [&](int r, const float2* rg) {
                float* bufp = s_chm + (r % 3) * 3072;
                #pragma unroll
                for (int i = 0; i < 6; ++i) {
                    if (i == 0 || r < 6) {
                        int lin = i * 256 + tid;
                        int dR = lin >> 4, c2 = lin & 15;
                        ((float2*)bufp)[dR * 16 + c2] = rg[i];
                    }
                }
            };
            auto fma_rows = [&](const float* cb, int rb, int wb, int nd) {
                #pragma unroll 4
                for (int dl = 0; dl < nd; ++dl) {
                    float4 wv = s_wW[jj][wb + dl];
                    float4 hv = *(const float4*)&cb[(rb + dl) * 32 + bg3 * 4];
                    a0.x = fmaf(hv.x, wv.x, a0.x); a0.y = fmaf(hv.x, wv.y, a0.y);
                    a0.z = fmaf(hv.x, wv.z, a0.z); a0.w = fmaf(hv.x, wv.w, a0.w);
                    a1.x = fmaf(hv.y, wv.x, a1.x); a1.y = fmaf(hv.y, wv.y, a1.y);
                    a1.z = fmaf(hv.y, wv.z, a1.z); a1.w = fmaf(hv.y, wv.w, a1.w);
                    a2.x = fmaf(hv.z, wv.x, a2.x); a2.y = fmaf(hv.z, wv.y, a2.y);
                    a2.z = fmaf(hv.z, wv.z, a2.z); a2.w = fmaf(hv.z, wv.w, a2.w);
                    a3.x = fmaf(hv.w, wv.x, a3.x); a3.y = fmaf(hv.w, wv.y, a3.y);
                    a3.z = fmaf(hv.w, wv.z, a3.z); a3.w = fmaf(hv.w, wv.w, a3.w);
                }
            };

            stage_issue(0, rgA);
            stage_issue(1, rgB);
            stage_write(0, rgA);
            __syncthreads();
            #pragma unroll 1
            for (int r = 0; r < 7; ++r) {
                if (r + 2 <= 6) stage_issue(r + 2, (r & 1) ? rgB : rgA);
                if (r + 1 <= 6) stage_write(r + 1, ((r + 1) & 1) ? rgB : rgA);
                __syncthreads();
                const float* cb = s_chm + (r % 3) * 3072;
                if (r < 6) fma_rows(cb, ks * 24, r * 96 + ks * 24, 24);
                else       fma_rows(cb, ks * 4,  r * 96 + ks * 4,  4);
            }
            // partial exchange: pitch-20 rows -> all 8 bank-quads evenly (bandwidth-min)
            {
                float* rd = s_chm + 3072;   // overlays buf1+buf2 (FMA(6) reads buf0 only)
                int R = ((ks * 8 + jj) << 3) + bg3;
                *(float4*)&rd[R * 20 + 0]  = a0;
                *(float4*)&rd[R * 20 + 4]  = a1;
                *(float4*)&rd[R * 20 + 8]  = a2;
                *(float4*)&rd[R * 20 + 12] = a3;
            }
            __syncthreads();
        }

        // pointwise LSTM: thread = (j, b)
        {
            const int jj_o = tid >> 5, bl = tid & 31;
            const int b = bblk * 32 + bl, j = jblk * 8 + jj_o;
            float4 s = s_wW[jj_o][595];  // fused bias
            if (t > 0) {
                const float* rd = s_chm + 3072;
                #pragma unroll
                for (int k2 = 0; k2 < 4; ++k2) {
                    int Rr = ((k2 * 8 + jj_o) << 3) + (bl >> 2);
                    float4 v = *(const float4*)&rd[Rr * 20 + (bl & 3) * 4];
                    s.x += v.x; s.y += v.y; s.z += v.z; s.w += v.w;
                }
            }
            const float* ip = seq_pt + ((size_t)t * BB + b) * 3;
            float x0 = ip[0], x1 = ip[1], x2 = ip[2];
            float4 wx0 = s_wW[jj_o][592], wx1 = s_wW[jj_o][593], wx2 = s_wW[jj_o][594];
            s.x += x0 * wx0.x + x1 * wx1.x + x2 * wx2.x;
            s.y += x0 * wx0.y + x1 * wx1.y + x2 * wx2.y;
            s.z += x0 * wx0.z + x1 * wx1.z + x2 * wx2.z;
            s.w += x0 * wx0.w + x1 * wx1.w + x2 * wx2.w;
            float ig = 1.f / (1.f + expf(-s.x));
            float fg = 1.f / (1.f + expf(-s.y));
            float gg = tanhf(s.z);
            float og = 1.f / (1.f + expf(-s.w));
            cell = fg * cell + ig * gg;
            float hval = og * tanhf(cell);
            st_scf(hAcur + (size_t)j * BB + b, hval);
            st_scf(hB + (size_t)b * HH + j, hval);
        }

        ++bar; gbar(syncp, g, tid, bar);   // h_t visible

        // ======== phase B ========
        {
            const int pb = (g < BB) ? g : (g - BB);
            float* s_h = s_chm;
            ((float2*)s_h)[tid] = ld_sc2(hB + (size_t)pb * HH + tid * 2);
            __syncthreads();
            float mk = seq_mask[(size_t)t * BB + pb];
            if (g < BB) {
                int m = tid & 31, oct = tid >> 5;
                if (m < 30) {
                    const float* wa = W_att + (size_t)m * HH + oct * 64;
                    const float* hb = s_h + oct * 64;
                    float acc = 0.f;
                    #pragma unroll 8
                    for (int d = 0; d < 64; ++d) acc = fmaf(hb[d], wa[d], acc);
                    s_pA[oct * 32 + m] = acc;
                }
                __syncthreads();
                if (tid < 30) {
                    float v = b_att[tid];
                    #pragma unroll
                    for (int o = 0; o < 8; ++o) v += s_pA[o * 32 + tid];
                    s_pB[tid] = v;
                }
                __syncthreads();
                if (tid < NATT) {
                    float ah = s_pB[tid], bh = s_pB[10 + tid], kh = s_pB[20 + tid];
                    float kprev = s_kk[tid];
                    float kn = kprev + expf(kh);
                    s_pB[32 + tid] = expf(ah);
                    s_pB[48 + tid] = expf(bh);
                    s_pB[64 + tid] = kn;
                    s_kk[tid] = mk * kn + (1.f - mk) * kprev;
                }
                __syncthreads();
                if (tid < UU) {
                    float uu = (float)tid;
                    float phi = 0.f;
                    #pragma unroll
                    for (int a = 0; a < NATT; ++a) {
                        float diff = s_pB[64 + a] - uu;
                        phi = fmaf(s_pB[32 + a], expf(-s_pB[48 + a] * diff * diff), phi);
                    }
                    s_phi[tid] = phi * c_mask[(size_t)tid * BB + pb];
                    s_ci[tid] = cidx[(size_t)tid * BB + pb];
                }
                __syncthreads();
                if (tid < NCH) {
                    float wn = 0.f;
                    for (int u = 0; u < UU; ++u)
                        wn += (s_ci[u] == tid) ? s_phi[u] : 0.f;
                    float wold = (t > 0) ? s_wold[tid] : 0.f;
                    float wnew = mk * wn + (1.f - mk) * wold;
                    s_wold[tid] = wnew;
                    st_scf(wT + (size_t)tid * BB + pb, wnew);
                }
            } else {
                if (tid < 242) {
                    int m = tid >> 1, hf = tid & 1;
                    const float* wm = W_mix + (size_t)m * 592 + hf * 256;
                    const float* hb = s_h + hf * 256;
                    float acc = 0.f;
                    #pragma unroll 8
                    for (int d = 0; d < 256; ++d) acc = fmaf(hb[d], wm[d], acc);
                    s_pA[tid] = acc;
                }
                __syncthreads();
                if (tid < 121)
                    st_scf(yh + (size_t)pb * 128 + tid, s_pA[2 * tid] + s_pA[2 * tid + 1]);
            }
        }

        ++bar; gbar(syncp, g, tid, bar);   // w_t, yh_t visible
    }

    // ======== final reduction ========
    if (g < BB && tid == 0) {
        st_scf(red + g, nll_acc);
        st_scf(red + BB + g, mask_acc);
    }
    ++bar; gbar(syncp, g, tid, bar);
    if (g == 0 && tid == 0) {
        float sn = 0.f, sm = 0.f;
        for (int i = 0; i < BB; ++i) { sn += ld_scf(red + i); sm += ld_scf(red + BB + i); }
        out[0] = sn / sm;
    }
}

extern "C" void kernel_launch(void* const* d_in, const int* in_sizes, int n_in,
                              void* d_out, int out_size, void* d_ws, size_t ws_size,
                              hipStream_t stream) {
    (void)in_sizes; (void)n_in; (void)out_size; (void)ws_size;
    const float* seq_pt   = (const float*)d_in[0];
    const float* seq_mask = (const float*)d_in[1];
    const float* tgt      = (const float*)d_in[2];
    const int*   cidx     = (const int*)d_in[3];
    const float* c_mask   = (const float*)d_in[4];
    const float* W_ih     = (const float*)d_in[5];
    const float* b_ih     = (const float*)d_in[6];
    const float* W_hh     = (const float*)d_in[7];
    const float* b_hh     = (const float*)d_in[8];
    const float* W_att    = (const float*)d_in[9];
    const float* b_att    = (const float*)d_in[10];
    const float* W_mix    = (const float*)d_in[11];
    const float* b_mix    = (const float*)d_in[12];
    float* out = (float*)d_out;
    float* ws  = (float*)d_ws;

    hipLaunchKernelGGL(init_sync_kernel, dim3(1), dim3(256), 0, stream, ws);

    void* args[] = {&seq_pt, &seq_mask, &tgt, &cidx, &c_mask,
                    &W_ih, &b_ih, &W_hh, &b_hh, &W_att, &b_att,
                    &W_mix, &b_mix, &out, &ws};
    hipError_t e = hipLaunchCooperativeKernel((void*)hw_kernel, dim3(256), dim3(256), args, 0, stream);
    if (e != hipSuccess) {
        (void)hipGetLastError();
        hipLaunchKernelGGL(hw_kernel, dim3(256), dim3(256), 0, stream,
                           seq_pt, seq_mask, tgt, cidx, c_mask,
                           W_ih, b_ih, W_hh, b_hh, W_att, b_att,
                           W_mix, b_mix, out, ws);
    }
}

// Round 5
// 20864.241 us; speedup vs baseline: 4.4368x; 1.1406x over previous
//
#include <hip/hip_runtime.h>

#define TSTEPS 1024
#define BB 128
#define HH 512
#define NCH 80
#define NATT 10
#define NG 20
#define UU 64
#define LOG2PI 1.8378770664093453f

// ws float offsets
#define OFF_HA0 0
#define OFF_HA1 65536
#define OFF_HB  131072
#define OFF_WT  196608
#define OFF_YH  206848
#define OFF_RED 223232
#define OFF_EP  223744      // unsigned h_ep[256], b_ep[256], red_cnt
#define EP_WORDS 520

__device__ __forceinline__ float ld_scf(const float* p) {
    return __hip_atomic_load((float*)p, __ATOMIC_RELAXED, __HIP_MEMORY_SCOPE_AGENT);
}
__device__ __forceinline__ void st_scf(float* p, float v) {
    __hip_atomic_store(p, v, __ATOMIC_RELAXED, __HIP_MEMORY_SCOPE_AGENT);
}
__device__ __forceinline__ float2 ld_sc2(const float* p) {
    unsigned long long v = __hip_atomic_load((unsigned long long*)p, __ATOMIC_RELAXED, __HIP_MEMORY_SCOPE_AGENT);
    float2 f; __builtin_memcpy(&f, &v, 8); return f;
}
__device__ __forceinline__ unsigned ld_u(const unsigned* p) {
    return __hip_atomic_load((unsigned*)p, __ATOMIC_RELAXED, __HIP_MEMORY_SCOPE_AGENT);
}
__device__ __forceinline__ void st_u(unsigned* p, unsigned v) {
    __hip_atomic_store(p, v, __ATOMIC_RELAXED, __HIP_MEMORY_SCOPE_AGENT);
}

__global__ void init_sync_kernel(float* ws) {
    unsigned* s = (unsigned*)(ws + OFF_EP);
    for (int i = threadIdx.x; i < EP_WORDS; i += blockDim.x) st_u(s + i, 0u);
}

__global__ __launch_bounds__(256)
void hw_kernel(const float* __restrict__ seq_pt, const float* __restrict__ seq_mask,
               const float* __restrict__ tgt, const int* __restrict__ cidx,
               const float* __restrict__ c_mask,
               const float* __restrict__ W_ih, const float* __restrict__ b_ih,
               const float* __restrict__ W_hh, const float* __restrict__ b_hh,
               const float* __restrict__ W_att, const float* __restrict__ b_att,
               const float* __restrict__ W_mix, const float* __restrict__ b_mix,
               float* __restrict__ out, float* __restrict__ ws)
{
    const int g = blockIdx.x;
    const int tid = threadIdx.x;
    const int jblk = g >> 2;          // 0..63 (8 hidden units)
    const int bblk = g & 3;           // 0..3  (32 batches)
    const bool isAttn = (jblk < 32);
    const int pb = bblk * 32 + (isAttn ? jblk : (jblk - 32));   // phase-B batch
    // phase-A FMA role
    const int jj  = tid & 7;
    const int bg3 = (tid >> 3) & 7;
    const int ks  = tid >> 6;         // wave = d-split

    __shared__ float4 s_wW[8][601];              // 76.9 KB
    __shared__ __align__(16) float s_chm[9216];  // 36.9 KB: 3 chunk buffers (partials/s_h overlay)
    __shared__ float s_y[124];
    __shared__ float s_pA[256], s_pB[96];
    __shared__ float s_wold[NCH], s_kk[16];
    __shared__ float s_phi[64];
    __shared__ int   s_ci[64];
    __shared__ float s_nA[20], s_nB[20], s_pen[1];

    // ---- persistent LDS weights ----
    for (int lin = tid; lin < 8 * 596; lin += 256) {
        int lj = lin / 596, idx = lin % 596;
        int jg = jblk * 8 + lj;
        float4 v;
        if (idx < 512) {
            v = make_float4(W_hh[(0 * HH + jg) * HH + idx], W_hh[(1 * HH + jg) * HH + idx],
                            W_hh[(2 * HH + jg) * HH + idx], W_hh[(3 * HH + jg) * HH + idx]);
        } else if (idx < 592) {
            int dd = 3 + (idx - 512);
            v = make_float4(W_ih[(0 * HH + jg) * 83 + dd], W_ih[(1 * HH + jg) * 83 + dd],
                            W_ih[(2 * HH + jg) * 83 + dd], W_ih[(3 * HH + jg) * 83 + dd]);
        } else if (idx < 595) {
            int dd = idx - 592;
            v = make_float4(W_ih[(0 * HH + jg) * 83 + dd], W_ih[(1 * HH + jg) * 83 + dd],
                            W_ih[(2 * HH + jg) * 83 + dd], W_ih[(3 * HH + jg) * 83 + dd]);
        } else {
            v = make_float4(b_ih[0 * HH + jg] + b_hh[0 * HH + jg], b_ih[1 * HH + jg] + b_hh[1 * HH + jg],
                            b_ih[2 * HH + jg] + b_hh[2 * HH + jg], b_ih[3 * HH + jg] + b_hh[3 * HH + jg]);
        }
        s_wW[lj][idx] = v;
    }
    if (tid < 16) s_kk[tid] = 0.f;
    if (tid < NCH) s_wold[tid] = 0.f;
    __syncthreads();

    unsigned* h_ep = (unsigned*)(ws + OFF_EP);
    unsigned* b_ep = h_ep + 256;
    unsigned* red_cnt = h_ep + 512;
    unsigned* h_grp = h_ep + bblk * 64;
    unsigned* b_grp = b_ep + bblk * 64;
    float* hB  = ws + OFF_HB;    // [b][d]
    float* wT  = ws + OFF_WT;    // [c][128]
    float* yh  = ws + OFF_YH;    // [b][128]
    float* red = ws + OFF_RED;

    float cell = 0.f, nll_acc = 0.f, mask_acc = 0.f;

    auto wait_slots = [&](const unsigned* base, int n, unsigned tgt_ep) {
        if (tid < n) {
            const unsigned* p = base + tid;
            while (ld_u(p) < tgt_ep) __builtin_amdgcn_s_sleep(1);
        }
        __syncthreads();
        asm volatile("" ::: "memory");
    };

    auto do_nll = [&](int tp) {   // attention WGs only; needs yh(tp), s_wold=w(tp)
        if (tid < 121) {
            const float* wr = W_mix + (size_t)tid * 592 + 512;   // cached read-only
            float acc = ld_scf(&yh[(size_t)pb * 128 + tid]) + b_mix[tid];
            #pragma unroll 8
            for (int c = 0; c < NCH; ++c) acc = fmaf(s_wold[c], wr[c], acc);
            s_y[tid] = acc;
        }
        __syncthreads();
        if (tid < 21) {
            const float* tg = tgt + ((size_t)tp * BB + pb) * 3;
            if (tid < NG) {
                int m = tid;
                float y0 = s_y[m], y1 = s_y[20 + m], y2 = s_y[40 + m];
                float y3 = s_y[60 + m], y4 = s_y[80 + m], y5 = s_y[100 + m];
                float x1 = tg[0], x2 = tg[1];
                float rho = tanhf(y5);
                float d1 = (x1 - y1) * expf(-y3);
                float d2 = (x2 - y2) * expf(-y4);
                float omr2 = 1.f - rho * rho;
                float Z = d1 * d1 + d2 * d2 - 2.f * rho * d1 * d2;
                float log_n = -Z / (2.f * omr2) - LOG2PI - y3 - y4 - 0.5f * logf(omr2);
                s_nA[m] = y0;
                s_nB[m] = y0 + log_n;
            } else {
                float yp = s_y[120];
                float pen = tg[2];
                float e = log1pf(expf(-fabsf(yp)));
                float ls_p = fminf(yp, 0.f) - e;
                float ls_n = fminf(-yp, 0.f) - e;
                s_pen[0] = -(pen * ls_p + (1.f - pen) * ls_n);
            }
        }
        __syncthreads();
        if (tid == 0) {
            float mx1 = -1e30f, mx2 = -1e30f;
            for (int m = 0; m < NG; ++m) { mx1 = fmaxf(mx1, s_nA[m]); mx2 = fmaxf(mx2, s_nB[m]); }
            float se1 = 0.f, se2 = 0.f;
            for (int m = 0; m < NG; ++m) { se1 += expf(s_nA[m] - mx1); se2 += expf(s_nB[m] - mx2); }
            float nll = (mx1 + logf(se1)) - (mx2 + logf(se2)) + s_pen[0];
            float mk = seq_mask[(size_t)tp * BB + pb];
            nll_acc += mk * nll;
            mask_acc += mk;
        }
        __syncthreads();
    };

    for (int t = 0; t < TSTEPS; ++t) {
        float* hAcur = ws + ((t & 1) ? OFF_HA1 : OFF_HA0);
        const float* hAprv = ws + ((t & 1) ? OFF_HA0 : OFF_HA1);

        // ======== phase A: staged chunks (7x96/16 rows), 3 buffers, 2-deep prefetch ========
        float4 a0 = make_float4(0.f, 0.f, 0.f, 0.f);
        float4 a1 = a0, a2 = a0, a3 = a0;

        if (t > 0) {
            float2 rgA[6], rgB[6];
            auto stage_issue = [&](int r, float2* rg) {
                #pragma unroll
                for (int i = 0; i < 6; ++i) {
                    if (i == 0 || r < 6) {
                        int lin = i * 256 + tid;
                        int dR = lin >> 4, c2 = lin & 15;
                        int R = r * 96 + dR;
                        const float* src = (R < 512) ? (hAprv + (size_t)R * BB)
                                                     : (wT + (size_t)(R - 512) * BB);
                        rg[i] = ld_sc2(src + bblk * 32 + c2 * 2);
                    }
                }
            };
            auto stage_write = [&](int r, const float2* rg) {
                float* bufp = s_chm + (r % 3) * 3072;
                #pragma unroll
                for (int i = 0; i < 6; ++i) {
                    if (i == 0 || r < 6) {
                        int lin = i * 256 + tid;
                        int dR = lin >> 4, c2 = lin & 15;
                        ((float2*)bufp)[dR * 16 + c2] = rg[i];
                    }
                }
            };
            auto fma_rows = [&](const float* cb, int rb, int wb, int nd) {
                #pragma unroll 4
                for (int dl = 0; dl < nd; ++dl) {
                    float4 wv = s_wW[jj][wb + dl];
                    float4 hv = *(const float4*)&cb[(rb + dl) * 32 + bg3 * 4];
                    a0.x = fmaf(hv.x, wv.x, a0.x); a0.y = fmaf(hv.x, wv.y, a0.y);
                    a0.z = fmaf(hv.x, wv.z, a0.z); a0.w = fmaf(hv.x, wv.w, a0.w);
                    a1.x = fmaf(hv.y, wv.x, a1.x); a1.y = fmaf(hv.y, wv.y, a1.y);
                    a1.z = fmaf(hv.y, wv.z, a1.z); a1.w = fmaf(hv.y, wv.w, a1.w);
                    a2.x = fmaf(hv.z, wv.x, a2.x); a2.y = fmaf(hv.z, wv.y, a2.y);
                    a2.z = fmaf(hv.z, wv.z, a2.z); a2.w = fmaf(hv.z, wv.w, a2.w);
                    a3.x = fmaf(hv.w, wv.x, a3.x); a3.y = fmaf(hv.w, wv.y, a3.y);
                    a3.z = fmaf(hv.w, wv.z, a3.z); a3.w = fmaf(hv.w, wv.w, a3.w);
                }
            };

            wait_slots(h_grp, 64, (unsigned)t);      // h(t-1) published by my bblk-group
            stage_issue(0, rgA);
            stage_issue(1, rgB);
            stage_write(0, rgA);
            __syncthreads();
            #pragma unroll 1
            for (int r = 0; r < 7; ++r) {
                if (r == 3) wait_slots(b_grp, 32, (unsigned)t);   // w(t-1) ready before chunk-5 issue
                if (r + 2 <= 6) stage_issue(r + 2, (r & 1) ? rgB : rgA);
                if (r + 1 <= 6) stage_write(r + 1, ((r + 1) & 1) ? rgB : rgA);
                __syncthreads();
                const float* cb = s_chm + (r % 3) * 3072;
                if (r < 6) fma_rows(cb, ks * 24, r * 96 + ks * 24, 24);
                else       fma_rows(cb, ks * 4,  r * 96 + ks * 4,  4);
            }
            {   // partial exchange, pitch-20 (bank-spread)
                float* rd = s_chm + 3072;
                int R = ((ks * 8 + jj) << 3) + bg3;
                *(float4*)&rd[R * 20 + 0]  = a0;
                *(float4*)&rd[R * 20 + 4]  = a1;
                *(float4*)&rd[R * 20 + 8]  = a2;
                *(float4*)&rd[R * 20 + 12] = a3;
            }
        }

        // mixture B(t-1) must be done before we overwrite hB/yh epoch-wise (also syncs partials)
        wait_slots(b_grp + 32, 32, (unsigned)t);

        // pointwise LSTM: thread = (j, b)
        {
            const int jj_o = tid >> 5, bl = tid & 31;
            const int b = bblk * 32 + bl, j = jblk * 8 + jj_o;
            float4 s = s_wW[jj_o][595];  // fused bias
            if (t > 0) {
                const float* rd = s_chm + 3072;
                #pragma unroll
                for (int k2 = 0; k2 < 4; ++k2) {
                    int Rr = ((k2 * 8 + jj_o) << 3) + (bl >> 2);
                    float4 v = *(const float4*)&rd[Rr * 20 + (bl & 3) * 4];
                    s.x += v.x; s.y += v.y; s.z += v.z; s.w += v.w;
                }
            }
            const float* ip = seq_pt + ((size_t)t * BB + b) * 3;
            float x0 = ip[0], x1 = ip[1], x2 = ip[2];
            float4 wx0 = s_wW[jj_o][592], wx1 = s_wW[jj_o][593], wx2 = s_wW[jj_o][594];
            s.x += x0 * wx0.x + x1 * wx1.x + x2 * wx2.x;
            s.y += x0 * wx0.y + x1 * wx1.y + x2 * wx2.y;
            s.z += x0 * wx0.z + x1 * wx1.z + x2 * wx2.z;
            s.w += x0 * wx0.w + x1 * wx1.w + x2 * wx2.w;
            float ig = 1.f / (1.f + expf(-s.x));
            float fg = 1.f / (1.f + expf(-s.y));
            float gg = tanhf(s.z);
            float og = 1.f / (1.f + expf(-s.w));
            cell = fg * cell + ig * gg;
            float hval = og * tanhf(cell);
            st_scf(hAcur + (size_t)j * BB + b, hval);
            st_scf(hB + (size_t)b * HH + j, hval);
        }
        asm volatile("s_waitcnt vmcnt(0)" ::: "memory");
        __syncthreads();
        if (tid == 0) st_u(&h_ep[bblk * 64 + jblk], (unsigned)(t + 1));   // h(t) published

        // NLL(t-1): yh(t-1) guaranteed by the b_grp+32 wait above
        if (isAttn && t > 0) do_nll(t - 1);

        // ======== phase B ========
        wait_slots(h_grp, 64, (unsigned)(t + 1));   // full h(t) for my group's batches
        {
            float* s_h = s_chm;
            ((float2*)s_h)[tid] = ld_sc2(hB + (size_t)pb * HH + tid * 2);
            __syncthreads();
            float mk = seq_mask[(size_t)t * BB + pb];
            if (isAttn) {
                int m = tid & 31, oct = tid >> 5;
                if (m < 30) {
                    const float* wa = W_att + (size_t)m * HH + oct * 64;
                    const float* hb = s_h + oct * 64;
                    float acc = 0.f;
                    #pragma unroll 8
                    for (int d = 0; d < 64; ++d) acc = fmaf(hb[d], wa[d], acc);
                    s_pA[oct * 32 + m] = acc;
                }
                __syncthreads();
                if (tid < 30) {
                    float v = b_att[tid];
                    #pragma unroll
                    for (int o = 0; o < 8; ++o) v += s_pA[o * 32 + tid];
                    s_pB[tid] = v;
                }
                __syncthreads();
                if (tid < NATT) {
                    float ah = s_pB[tid], bh = s_pB[10 + tid], kh = s_pB[20 + tid];
                    float kprev = s_kk[tid];
                    float kn = kprev + expf(kh);
                    s_pB[32 + tid] = expf(ah);
                    s_pB[48 + tid] = expf(bh);
                    s_pB[64 + tid] = kn;
                    s_kk[tid] = mk * kn + (1.f - mk) * kprev;
                }
                __syncthreads();
                if (tid < UU) {
                    float uu = (float)tid;
                    float phi = 0.f;
                    #pragma unroll
                    for (int a = 0; a < NATT; ++a) {
                        float diff = s_pB[64 + a] - uu;
                        phi = fmaf(s_pB[32 + a], expf(-s_pB[48 + a] * diff * diff), phi);
                    }
                    s_phi[tid] = phi * c_mask[(size_t)tid * BB + pb];
                    s_ci[tid] = cidx[(size_t)tid * BB + pb];
                }
                __syncthreads();
                if (tid < NCH) {
                    float wn = 0.f;
                    for (int u = 0; u < UU; ++u)
                        wn += (s_ci[u] == tid) ? s_phi[u] : 0.f;
                    float wold = (t > 0) ? s_wold[tid] : 0.f;
                    float wnew = mk * wn + (1.f - mk) * wold;
                    s_wold[tid] = wnew;
                    st_scf(wT + (size_t)tid * BB + pb, wnew);
                }
            } else {
                if (tid < 242) {
                    int m = tid >> 1, hf = tid & 1;
                    const float* wm = W_mix + (size_t)m * 592 + hf * 256;
                    const float* hb = s_h + hf * 256;
                    float acc = 0.f;
                    #pragma unroll 8
                    for (int d = 0; d < 256; ++d) acc = fmaf(hb[d], wm[d], acc);
                    s_pA[tid] = acc;
                }
                __syncthreads();
                if (tid < 121)
                    st_scf(yh + (size_t)pb * 128 + tid, s_pA[2 * tid] + s_pA[2 * tid + 1]);
            }
        }
        asm volatile("s_waitcnt vmcnt(0)" ::: "memory");
        __syncthreads();
        if (tid == 0) st_u(&b_ep[bblk * 64 + jblk], (unsigned)(t + 1));   // w(t)/yh(t) published
    }

    // ======== epilogue: NLL(1023) + reduction ========
    if (isAttn) {
        wait_slots(b_grp + 32, 32, (unsigned)TSTEPS);   // yh(1023) ready
        do_nll(TSTEPS - 1);
        if (tid == 0) {
            st_scf(red + pb, nll_acc);
            st_scf(red + BB + pb, mask_acc);
        }
        asm volatile("s_waitcnt vmcnt(0)" ::: "memory");
        __syncthreads();
        if (tid == 0)
            __hip_atomic_fetch_add(red_cnt, 1u, __ATOMIC_RELAXED, __HIP_MEMORY_SCOPE_AGENT);
    }
    if (g == 0) {
        if (tid == 0) {
            while (ld_u(red_cnt) < 128u) __builtin_amdgcn_s_sleep(2);
            asm volatile("" ::: "memory");
            float sn = 0.f, sm = 0.f;
            for (int i = 0; i < BB; ++i) { sn += ld_scf(red + i); sm += ld_scf(red + BB + i); }
            out[0] = sn / sm;
        }
    }
}

extern "C" void kernel_launch(void* const* d_in, const int* in_sizes, int n_in,
                              void* d_out, int out_size, void* d_ws, size_t ws_size,
                              hipStream_t stream) {
    (void)in_sizes; (void)n_in; (void)out_size; (void)ws_size;
    const float* seq_pt   = (const float*)d_in[0];
    const float* seq_mask = (const float*)d_in[1];
    const float* tgt      = (const float*)d_in[2];
    const int*   cidx     = (const int*)d_in[3];
    const float* c_mask   = (const float*)d_in[4];
    const float* W_ih     = (const float*)d_in[5];
    const float* b_ih     = (const float*)d_in[6];
    const float* W_hh     = (const float*)d_in[7];
    const float* b_hh     = (const float*)d_in[8];
    const float* W_att    = (const float*)d_in[9];
    const float* b_att    = (const float*)d_in[10];
    const float* W_mix    = (const float*)d_in[11];
    const float* b_mix    = (const float*)d_in[12];
    float* out = (float*)d_out;
    float* ws  = (float*)d_ws;

    hipLaunchKernelGGL(init_sync_kernel, dim3(1), dim3(256), 0, stream, ws);
    hipLaunchKernelGGL(hw_kernel, dim3(256), dim3(256), 0, stream,
                       seq_pt, seq_mask, tgt, cidx, c_mask,
                       W_ih, b_ih, W_hh, b_hh, W_att, b_att,
                       W_mix, b_mix, out, ws);
}